// Round 2
// baseline (453.966 us; speedup 1.0000x reference)
//
#include <hip/hip_runtime.h>
#include <hip/hip_bf16.h>

typedef __bf16 bf16;
typedef __bf16 bf16x4v __attribute__((ext_vector_type(4)));
typedef __bf16 bf16x8v __attribute__((ext_vector_type(8)));
typedef float f32x4 __attribute__((ext_vector_type(4)));

#define DEVINL static __device__ __forceinline__

DEVINL f32x4 mfma16(bf16x8v a, bf16x8v b, f32x4 c) {
  return __builtin_amdgcn_mfma_f32_16x16x32_bf16(a, b, c, 0, 0, 0);
}

// ---------------- style projections: s = style @ w_ada + b_ada (f32) --------
__global__ __launch_bounds__(256) void k_style(
    const float* __restrict__ style,
    const float* __restrict__ wa1, const float* __restrict__ ba1,
    const float* __restrict__ wa2, const float* __restrict__ ba2,
    float* __restrict__ s1, float* __restrict__ s2) {
  int idx = blockIdx.x * 256 + threadIdx.x;   // 2*16*512 = 16384
  int which = idx >> 13;
  int r = idx & 8191;
  int b = r >> 9, n = r & 511;
  const float* wa = which ? wa2 : wa1;
  const float* ba = which ? ba2 : ba1;
  const float* srow = style + b * 512;
  float acc = ba[n];
  for (int k = 0; k < 512; ++k)
    acc += srow[k] * wa[k * 512 + n];
  (which ? s2 : s1)[b * 512 + n] = acc;
}

// ---------------- per-(b,c) mean/var over L=4096 -> adain scale/shift -------
template<int F32>
__global__ __launch_bounds__(256) void k_stats(
    const void* __restrict__ xv, const float* __restrict__ s,
    float* __restrict__ scale, float* __restrict__ shift) {
  int b = blockIdx.y, cg = blockIdx.x;        // cg: 0..3 (64 channels each)
  int tid = threadIdx.x;
  int cq = tid & 15, rg = tid >> 4;           // 16 col-quads x 16 row-groups
  size_t base = (size_t)b * 4096 * 256 + cg * 64 + cq * 4;
  float sm0=0,sm1=0,sm2=0,sm3=0, q0=0,q1=0,q2=0,q3=0;
  for (int it = 0; it < 256; ++it) {
    size_t ofs = base + (size_t)(rg + it * 16) * 256;
    float f0, f1, f2, f3;
    if constexpr (F32) {
      f32x4 v = *(const f32x4*)&((const float*)xv)[ofs];
      f0=v[0]; f1=v[1]; f2=v[2]; f3=v[3];
    } else {
      bf16x4v v = *(const bf16x4v*)&((const bf16*)xv)[ofs];
      f0=(float)v[0]; f1=(float)v[1]; f2=(float)v[2]; f3=(float)v[3];
    }
    sm0+=f0; q0+=f0*f0; sm1+=f1; q1+=f1*f1;
    sm2+=f2; q2+=f2*f2; sm3+=f3; q3+=f3*f3;
  }
  #pragma unroll
  for (int m = 16; m <= 32; m <<= 1) {
    sm0 += __shfl_xor(sm0, m); sm1 += __shfl_xor(sm1, m);
    sm2 += __shfl_xor(sm2, m); sm3 += __shfl_xor(sm3, m);
    q0  += __shfl_xor(q0,  m); q1  += __shfl_xor(q1,  m);
    q2  += __shfl_xor(q2,  m); q3  += __shfl_xor(q3,  m);
  }
  __shared__ float red[2][4][16][4];
  int l = tid & 63, w = tid >> 6;
  if (l < 16) {
    red[0][w][cq][0]=sm0; red[0][w][cq][1]=sm1; red[0][w][cq][2]=sm2; red[0][w][cq][3]=sm3;
    red[1][w][cq][0]=q0;  red[1][w][cq][1]=q1;  red[1][w][cq][2]=q2;  red[1][w][cq][3]=q3;
  }
  __syncthreads();
  if (tid < 64) {
    int cq2 = tid >> 2, u = tid & 3;
    float S=0.f, Q=0.f;
    #pragma unroll
    for (int ww = 0; ww < 4; ++ww) { S += red[0][ww][cq2][u]; Q += red[1][ww][cq2][u]; }
    float mean = S * (1.0f/4096.0f);
    float var  = Q * (1.0f/4096.0f) - mean*mean;
    float inv  = rsqrtf(var + 1e-5f);
    int c = cg*64 + cq2*4 + u;
    float mu_s  = s[b*512 + c];
    float std_s = s[b*512 + 256 + c];
    float sc = std_s * inv;
    scale[b*256 + c] = sc;
    shift[b*256 + c] = mu_s - sc * mean;
  }
}

// ---------------- weight transpose+cvt (K x N f32) -> (N x K bf16) ----------
__global__ __launch_bounds__(256) void k_tr(
    const float* __restrict__ in, bf16* __restrict__ out, int K, int N) {
  __shared__ float t[32][33];
  int bx = blockIdx.x * 32, by = blockIdx.y * 32;
  int tx = threadIdx.x & 31, ty = threadIdx.x >> 5;
  #pragma unroll
  for (int r = 0; r < 32; r += 8)
    t[ty + r][tx] = in[(size_t)(by + ty + r) * N + bx + tx];
  __syncthreads();
  #pragma unroll
  for (int r = 0; r < 32; r += 8)
    out[(size_t)(bx + ty + r) * K + by + tx] = (bf16)t[tx][ty + r];
}

// ---------------- GEMM stage helpers ----------------------------------------
// LDS tiles 128x64 bf16, chunk-XOR swizzled (chunk ^= row&7), 16B stores.
template<int ADAIN>
DEVINL void stage_bf16(bf16* sw, const bf16* __restrict__ src, int ld,
                       int row0, int k0, int tid, int row_off,
                       const float* __restrict__ scale,
                       const float* __restrict__ shift) {
  #pragma unroll
  for (int i = 0; i < 4; ++i) {
    int idx = i * 256 + tid;               // 1024 16B-chunks
    int r = idx >> 3, c = idx & 7;
    bf16x8v v = *(const bf16x8v*)&src[(size_t)(row0 + r) * ld + k0 + c * 8];
    if constexpr (ADAIN) {
      int bb = (row0 + r + row_off) >> 12;
      const float* sc = &scale[bb * 256 + k0 + c * 8];
      const float* sh = &shift[bb * 256 + k0 + c * 8];
      #pragma unroll
      for (int u = 0; u < 8; ++u) v[u] = (bf16)(sh[u] + sc[u] * (float)v[u]);
    }
    *(bf16x8v*)&sw[r * 64 + ((c ^ (r & 7)) * 8)] = v;
  }
}

template<int ADAIN>
DEVINL void stage_f32(bf16* sw, const float* __restrict__ src, int ld,
                      int row0, int k0, int tid, int row_off,
                      const float* __restrict__ scale,
                      const float* __restrict__ shift) {
  #pragma unroll
  for (int i = 0; i < 4; ++i) {
    int idx = i * 256 + tid;
    int r = idx >> 3, c = idx & 7;
    const float* p = &src[(size_t)(row0 + r) * ld + k0 + c * 8];
    f32x4 v0 = *(const f32x4*)p;
    f32x4 v1 = *(const f32x4*)(p + 4);
    float f[8] = {v0[0],v0[1],v0[2],v0[3],v1[0],v1[1],v1[2],v1[3]};
    if constexpr (ADAIN) {
      int bb = (row0 + r + row_off) >> 12;
      const float* sc = &scale[bb * 256 + k0 + c * 8];
      const float* sh = &shift[bb * 256 + k0 + c * 8];
      #pragma unroll
      for (int u = 0; u < 8; ++u) f[u] = sh[u] + sc[u] * f[u];
    }
    bf16x8v o;
    #pragma unroll
    for (int u = 0; u < 8; ++u) o[u] = (bf16)f[u];
    *(bf16x8v*)&sw[r * 64 + ((c ^ (r & 7)) * 8)] = o;
  }
}

// ---------------- GEMM: out = [adain(A)] @ Bt^T + bias (+res, gelu) ---------
// A: MxK row-major (f32 or bf16), Bt: NxK row-major bf16. 128x128 tile.
// RESMODE: 0 none, 1 f32, 2 bf16. OUTF32: 1 f32 out, 0 bf16 out.
template<int AF32, int ADAIN, int RESMODE, int GELU, int OUTF32>
__global__ __launch_bounds__(256) void k_gemm(
    const void* __restrict__ Av, const bf16* __restrict__ Bt,
    const float* __restrict__ bias, const void* __restrict__ resv,
    const float* __restrict__ scale, const float* __restrict__ shift,
    void* __restrict__ outv, int N, int K, int row_off) {
  __shared__ bf16 a_sw[128 * 64];
  __shared__ bf16 b_sw[128 * 64];
  int tid = threadIdx.x;
  int l = tid & 63, w = tid >> 6;
  int wr = w >> 1, wc = w & 1;             // 2x2 waves, 64x64 each
  int lm = l & 15, lg = l >> 4;
  int m0 = blockIdx.y * 128, n0 = blockIdx.x * 128;

  f32x4 acc[4][4];
  #pragma unroll
  for (int mi = 0; mi < 4; ++mi)
    #pragma unroll
    for (int ni = 0; ni < 4; ++ni)
      acc[mi][ni] = (f32x4){0.f, 0.f, 0.f, 0.f};

  for (int k0 = 0; k0 < K; k0 += 64) {
    if constexpr (AF32)
      stage_f32<ADAIN>(a_sw, (const float*)Av, K, m0, k0, tid, row_off, scale, shift);
    else
      stage_bf16<ADAIN>(a_sw, (const bf16*)Av, K, m0, k0, tid, row_off, scale, shift);
    stage_bf16<0>(b_sw, Bt, K, n0, k0, tid, 0, nullptr, nullptr);
    __syncthreads();
    #pragma unroll
    for (int kk = 0; kk < 2; ++kk) {
      bf16x8v af[4], bv[4];
      #pragma unroll
      for (int mi = 0; mi < 4; ++mi) {
        int row = wr * 64 + mi * 16 + lm;
        af[mi] = *(const bf16x8v*)&a_sw[row * 64 + (((kk * 4 + lg) ^ (row & 7)) * 8)];
      }
      #pragma unroll
      for (int ni = 0; ni < 4; ++ni) {
        int row = wc * 64 + ni * 16 + lm;
        bv[ni] = *(const bf16x8v*)&b_sw[row * 64 + (((kk * 4 + lg) ^ (row & 7)) * 8)];
      }
      #pragma unroll
      for (int mi = 0; mi < 4; ++mi)
        #pragma unroll
        for (int ni = 0; ni < 4; ++ni)
          acc[mi][ni] = mfma16(af[mi], bv[ni], acc[mi][ni]);
    }
    __syncthreads();
  }
  #pragma unroll
  for (int mi = 0; mi < 4; ++mi) {
    #pragma unroll
    for (int ni = 0; ni < 4; ++ni) {
      int row = m0 + wr * 64 + mi * 16 + lg * 4;
      int col = n0 + wc * 64 + ni * 16 + lm;
      float bv_ = bias[col];
      #pragma unroll
      for (int j = 0; j < 4; ++j) {
        float o = acc[mi][ni][j] + bv_;
        if constexpr (RESMODE == 1)
          o += ((const float*)resv)[(size_t)(row + j) * N + col];
        if constexpr (RESMODE == 2)
          o += (float)((const bf16*)resv)[(size_t)(row + j) * N + col];
        if constexpr (GELU)
          o = 0.5f * o * (1.0f + erff(o * 0.70710678118654752f));
        if constexpr (OUTF32)
          ((float*)outv)[(size_t)(row + j) * N + col] = o;
        else
          ((bf16*)outv)[(size_t)(row + j) * N + col] = (bf16)o;
      }
    }
  }
}

// ---------------- windowed attention (both branches) ------------------------
// block = (b, window, branch); 4 waves = 4 heads (d=32), N=64 tokens.
__global__ __launch_bounds__(256) void k_attn(
    const bf16* __restrict__ qkv,
    const float* __restrict__ rpb1, const float* __restrict__ rpb2,
    bf16* __restrict__ aout) {
  __shared__ bf16 lds[27648];
  bf16* vt = lds;             // [128][72]   V transposed (d-major)
  bf16* qs = lds + 9216;      // [64][136]
  bf16* ks = lds + 17920;     // [64][136]
  bf16* ps = lds + 9216;      // [4][64][72] reuses qs/ks after frag loads

  int tid = threadIdx.x;
  int bx = blockIdx.x;
  int br = bx & 1, widx = (bx >> 1) & 63, b = bx >> 7;
  int wy = widx >> 3, wx = widx & 7;

  auto grow = [&](int tok) -> int {
    int y = wy * 8 + (tok >> 3), xc = wx * 8 + (tok & 7);
    if (br) { y = (y + 4) & 63; xc = (xc + 4) & 63; }   // shifted branch
    return b * 4096 + y * 64 + xc;
  };

  // stage Q, K row-major
  #pragma unroll
  for (int m = 0; m < 2; ++m) {
    bf16* dst = m ? ks : qs;
    int moff = m * 256 + br * 128;
    for (int it = 0; it < 4; ++it) {
      int task = it * 256 + tid;
      int tok = task >> 4, chunk = task & 15;
      bf16x8v v = *(const bf16x8v*)&qkv[(size_t)grow(tok) * 768 + moff + chunk * 8];
      *(bf16x8v*)&dst[tok * 136 + chunk * 8] = v;
    }
  }
  // stage V transposed
  for (int it = 0; it < 4; ++it) {
    int task = it * 256 + tid;
    int tok = task & 63, chunk = task >> 6;
    bf16x8v v = *(const bf16x8v*)&qkv[(size_t)grow(tok) * 768 + 512 + br * 128 + chunk * 8];
    #pragma unroll
    for (int u = 0; u < 8; ++u) vt[(chunk * 8 + u) * 72 + tok] = v[u];
  }
  __syncthreads();

  int l = tid & 63, h = tid >> 6;
  int lm = l & 15, lg = l >> 4;

  bf16x8v qa[4], kb[4];
  #pragma unroll
  for (int i = 0; i < 4; ++i) {
    qa[i] = *(const bf16x8v*)&qs[(i * 16 + lm) * 136 + h * 32 + lg * 8];
    kb[i] = *(const bf16x8v*)&ks[(i * 16 + lm) * 136 + h * 32 + lg * 8];
  }
  __syncthreads();   // all waves done with qs/ks -> ps region reusable

  f32x4 s[4][4];
  #pragma unroll
  for (int qi = 0; qi < 4; ++qi)
    #pragma unroll
    for (int ki = 0; ki < 4; ++ki)
      s[qi][ki] = mfma16(qa[qi], kb[ki], (f32x4){0.f,0.f,0.f,0.f});

  const float* rpb = br ? rpb2 : rpb1;
  bool need_mask = br && (wy == 7 || wx == 7);
  #pragma unroll
  for (int qi = 0; qi < 4; ++qi)
    #pragma unroll
    for (int ki = 0; ki < 4; ++ki)
      #pragma unroll
      for (int j = 0; j < 4; ++j) {
        int iq = qi * 16 + lg * 4 + j;     // C/D: row=(lane>>4)*4+reg
        int ik = ki * 16 + lm;             //      col=lane&15
        int dy = (iq >> 3) - (ik >> 3) + 7;
        int dx = (iq & 7) - (ik & 7) + 7;
        float val = s[qi][ki][j] * 0.17677669529663687f + rpb[(dy * 15 + dx) * 4 + h];
        if (need_mask) {
          int yq = wy * 8 + (iq >> 3), xq = wx * 8 + (iq & 7);
          int yk = wy * 8 + (ik >> 3), xk = wx * 8 + (ik & 7);
          int idq = (yq < 56 ? 0 : (yq < 60 ? 1 : 2)) * 3 + (xq < 56 ? 0 : (xq < 60 ? 1 : 2));
          int idk = (yk < 56 ? 0 : (yk < 60 ? 1 : 2)) * 3 + (xk < 56 ? 0 : (xk < 60 ? 1 : 2));
          if (idq != idk) val -= 100.0f;
        }
        s[qi][ki][j] = val;
      }

  // softmax per q-row (cols spread over 16 lanes x 4 ki frags)
  #pragma unroll
  for (int qi = 0; qi < 4; ++qi)
    #pragma unroll
    for (int j = 0; j < 4; ++j) {
      float mx = fmaxf(fmaxf(s[qi][0][j], s[qi][1][j]), fmaxf(s[qi][2][j], s[qi][3][j]));
      #pragma unroll
      for (int mk = 1; mk <= 8; mk <<= 1) mx = fmaxf(mx, __shfl_xor(mx, mk));
      float sum = 0.f;
      #pragma unroll
      for (int ki = 0; ki < 4; ++ki) {
        float e = __expf(s[qi][ki][j] - mx);
        s[qi][ki][j] = e;
        sum += e;
      }
      #pragma unroll
      for (int mk = 1; mk <= 8; mk <<= 1) sum += __shfl_xor(sum, mk);
      float rs = 1.0f / sum;
      #pragma unroll
      for (int ki = 0; ki < 4; ++ki) s[qi][ki][j] *= rs;
    }

  // P -> per-wave LDS (bf16), then PV
  bf16* pw = ps + h * 4608;
  #pragma unroll
  for (int qi = 0; qi < 4; ++qi)
    #pragma unroll
    for (int ki = 0; ki < 4; ++ki)
      #pragma unroll
      for (int j = 0; j < 4; ++j)
        pw[(qi * 16 + lg * 4 + j) * 72 + ki * 16 + lm] = (bf16)s[qi][ki][j];

  f32x4 o[4][2];
  #pragma unroll
  for (int qi = 0; qi < 4; ++qi) {
    o[qi][0] = (f32x4){0.f,0.f,0.f,0.f};
    o[qi][1] = (f32x4){0.f,0.f,0.f,0.f};
  }
  #pragma unroll
  for (int kk = 0; kk < 2; ++kk) {
    bf16x8v pa[4], vb[2];
    #pragma unroll
    for (int qi = 0; qi < 4; ++qi)
      pa[qi] = *(const bf16x8v*)&pw[(qi * 16 + lm) * 72 + kk * 32 + lg * 8];
    #pragma unroll
    for (int ni = 0; ni < 2; ++ni)
      vb[ni] = *(const bf16x8v*)&vt[(h * 32 + ni * 16 + lm) * 72 + kk * 32 + lg * 8];
    #pragma unroll
    for (int qi = 0; qi < 4; ++qi)
      #pragma unroll
      for (int ni = 0; ni < 2; ++ni)
        o[qi][ni] = mfma16(pa[qi], vb[ni], o[qi][ni]);
  }

  #pragma unroll
  for (int qi = 0; qi < 4; ++qi)
    #pragma unroll
    for (int ni = 0; ni < 2; ++ni)
      #pragma unroll
      for (int j = 0; j < 4; ++j) {
        int tok = qi * 16 + lg * 4 + j;
        int row = grow(tok);
        int col = br * 128 + h * 32 + ni * 16 + lm;
        aout[(size_t)row * 256 + col] = (bf16)o[qi][ni][j];
      }
}

// ---------------- host ------------------------------------------------------
extern "C" void kernel_launch(void* const* d_in, const int* in_sizes, int n_in,
                              void* d_out, int out_size, void* d_ws, size_t ws_size,
                              hipStream_t stream) {
  (void)in_sizes; (void)n_in; (void)out_size; (void)ws_size;
  const float* x      = (const float*)d_in[0];
  const float* style  = (const float*)d_in[1];
  const float* w_qkv  = (const float*)d_in[2];
  const float* b_qkv  = (const float*)d_in[3];
  const float* w_proj = (const float*)d_in[4];
  const float* b_proj = (const float*)d_in[5];
  const float* w_ada1 = (const float*)d_in[6];
  const float* b_ada1 = (const float*)d_in[7];
  const float* w_ada2 = (const float*)d_in[8];
  const float* b_ada2 = (const float*)d_in[9];
  const float* rpb1   = (const float*)d_in[10];
  const float* rpb2   = (const float*)d_in[11];
  const float* w_fc1  = (const float*)d_in[12];
  const float* b_fc1  = (const float*)d_in[13];
  const float* w_fc2  = (const float*)d_in[14];
  const float* b_fc2  = (const float*)d_in[15];

  char* ws = (char*)d_ws;
  float* s1     = (float*)(ws + 0);
  float* s2     = (float*)(ws + 32768);
  float* scale1 = (float*)(ws + 65536);
  float* shift1 = (float*)(ws + 81920);
  float* scale2 = (float*)(ws + 98304);
  float* shift2 = (float*)(ws + 114688);
  bf16* wtqkv   = (bf16*)(ws + 131072);            // 768x256 bf16
  bf16* wtproj  = (bf16*)(ws + 524288);            // 256x256
  bf16* wtfc1   = (bf16*)(ws + 655360);            // 1024x256
  bf16* wtfc2   = (bf16*)(ws + 1179648);           // 256x1024
  const size_t BIG = 2097152;
  bf16* qkv  = (bf16*)(ws + BIG);                  // 65536x768 bf16 (100.7MB)
  bf16* attn = (bf16*)(ws + BIG + 100663296);      // 65536x256 bf16 (33.5MB)
  bf16* x1   = (bf16*)(ws + BIG);                  // 65536x256 bf16 (reuses qkv)
  bf16* g    = (bf16*)(ws + BIG + 33554432);       // 32768x1024 bf16 chunk (67MB)

  // weight transposes (f32 -> bf16)
  k_tr<<<dim3(24, 8),  256, 0, stream>>>(w_qkv,  wtqkv,  256, 768);
  k_tr<<<dim3(8, 8),   256, 0, stream>>>(w_proj, wtproj, 256, 256);
  k_tr<<<dim3(32, 8),  256, 0, stream>>>(w_fc1,  wtfc1,  256, 1024);
  k_tr<<<dim3(8, 32),  256, 0, stream>>>(w_fc2,  wtfc2,  1024, 256);

  // style projections, adain1 params
  k_style<<<64, 256, 0, stream>>>(style, w_ada1, b_ada1, w_ada2, b_ada2, s1, s2);
  k_stats<1><<<dim3(4, 16), 256, 0, stream>>>(x, s1, scale1, shift1);

  // qkv = adain1(x) @ w_qkv + b_qkv           (A f32+adain, out bf16)
  k_gemm<1,1,0,0,0><<<dim3(6, 512), 256, 0, stream>>>(
      x, wtqkv, b_qkv, nullptr, scale1, shift1, qkv, 768, 256, 0);

  // windowed attention (both branches)
  k_attn<<<2048, 256, 0, stream>>>(qkv, rpb1, rpb2, attn);

  // x1 = x + attn @ w_proj + b_proj           (A bf16, res f32, out bf16)
  k_gemm<0,0,1,0,0><<<dim3(2, 512), 256, 0, stream>>>(
      attn, wtproj, b_proj, x, nullptr, nullptr, x1, 256, 256, 0);

  // adain2 params from x1 (bf16)
  k_stats<0><<<dim3(4, 16), 256, 0, stream>>>(x1, s2, scale2, shift2);

  // MLP in 2 row-chunks of 32768 (g reuses dead qkv tail region)
  for (int ch = 0; ch < 2; ++ch) {
    size_t ro = (size_t)ch * 32768;
    // g = gelu(adain2(x1) @ w_fc1 + b_fc1)    (A bf16+adain, out bf16)
    k_gemm<0,1,0,1,0><<<dim3(8, 256), 256, 0, stream>>>(
        x1 + ro * 256, wtfc1, b_fc1, nullptr, scale2, shift2,
        g, 1024, 256, (int)ro);
    // out = x1 + g @ w_fc2 + b_fc2            (A bf16, res bf16, out f32)
    k_gemm<0,0,2,0,1><<<dim3(2, 256), 256, 0, stream>>>(
        g, wtfc2, b_fc2, x1 + ro * 256, nullptr, nullptr,
        (float*)d_out + ro * 256, 256, 1024, 0);
  }
}

// Round 3
// 391.037 us; speedup vs baseline: 1.1609x; 1.1609x over previous
//
#include <hip/hip_runtime.h>
#include <hip/hip_bf16.h>

typedef __bf16 bf16;
typedef __bf16 bf16x4v __attribute__((ext_vector_type(4)));
typedef __bf16 bf16x8v __attribute__((ext_vector_type(8)));
typedef float f32x4 __attribute__((ext_vector_type(4)));

#define DEVINL static __device__ __forceinline__

DEVINL f32x4 mfma16(bf16x8v a, bf16x8v b, f32x4 c) {
  return __builtin_amdgcn_mfma_f32_16x16x32_bf16(a, b, c, 0, 0, 0);
}

// ---------------- style projections: s = style @ w_ada + b_ada (f32) --------
__global__ __launch_bounds__(256) void k_style(
    const float* __restrict__ style,
    const float* __restrict__ wa1, const float* __restrict__ ba1,
    const float* __restrict__ wa2, const float* __restrict__ ba2,
    float* __restrict__ s1, float* __restrict__ s2) {
  int idx = blockIdx.x * 256 + threadIdx.x;   // 2*16*512 = 16384
  int which = idx >> 13;
  int r = idx & 8191;
  int b = r >> 9, n = r & 511;
  const float* wa = which ? wa2 : wa1;
  const float* ba = which ? ba2 : ba1;
  const float* srow = style + b * 512;
  float acc = ba[n];
  for (int k = 0; k < 512; ++k)
    acc += srow[k] * wa[k * 512 + n];
  (which ? s2 : s1)[b * 512 + n] = acc;
}

// ---------------- per-(b,c) mean/var over L=4096 -> adain scale/shift -------
template<int F32>
__global__ __launch_bounds__(256) void k_stats(
    const void* __restrict__ xv, const float* __restrict__ s,
    float* __restrict__ scale, float* __restrict__ shift) {
  int b = blockIdx.y, cg = blockIdx.x;        // cg: 0..3 (64 channels each)
  int tid = threadIdx.x;
  int cq = tid & 15, rg = tid >> 4;           // 16 col-quads x 16 row-groups
  size_t base = (size_t)b * 4096 * 256 + cg * 64 + cq * 4;
  float sm0=0,sm1=0,sm2=0,sm3=0, q0=0,q1=0,q2=0,q3=0;
  for (int it = 0; it < 256; ++it) {
    size_t ofs = base + (size_t)(rg + it * 16) * 256;
    float f0, f1, f2, f3;
    if constexpr (F32) {
      f32x4 v = *(const f32x4*)&((const float*)xv)[ofs];
      f0=v[0]; f1=v[1]; f2=v[2]; f3=v[3];
    } else {
      bf16x4v v = *(const bf16x4v*)&((const bf16*)xv)[ofs];
      f0=(float)v[0]; f1=(float)v[1]; f2=(float)v[2]; f3=(float)v[3];
    }
    sm0+=f0; q0+=f0*f0; sm1+=f1; q1+=f1*f1;
    sm2+=f2; q2+=f2*f2; sm3+=f3; q3+=f3*f3;
  }
  #pragma unroll
  for (int m = 16; m <= 32; m <<= 1) {
    sm0 += __shfl_xor(sm0, m); sm1 += __shfl_xor(sm1, m);
    sm2 += __shfl_xor(sm2, m); sm3 += __shfl_xor(sm3, m);
    q0  += __shfl_xor(q0,  m); q1  += __shfl_xor(q1,  m);
    q2  += __shfl_xor(q2,  m); q3  += __shfl_xor(q3,  m);
  }
  __shared__ float red[2][4][16][4];
  int w = tid >> 6;
  if ((tid & 63) < 16) {
    red[0][w][cq][0]=sm0; red[0][w][cq][1]=sm1; red[0][w][cq][2]=sm2; red[0][w][cq][3]=sm3;
    red[1][w][cq][0]=q0;  red[1][w][cq][1]=q1;  red[1][w][cq][2]=q2;  red[1][w][cq][3]=q3;
  }
  __syncthreads();
  if (tid < 64) {
    int cq2 = tid >> 2, u = tid & 3;
    float S=0.f, Q=0.f;
    #pragma unroll
    for (int ww = 0; ww < 4; ++ww) { S += red[0][ww][cq2][u]; Q += red[1][ww][cq2][u]; }
    float mean = S * (1.0f/4096.0f);
    float var  = Q * (1.0f/4096.0f) - mean*mean;
    float inv  = rsqrtf(var + 1e-5f);
    int c = cg*64 + cq2*4 + u;
    float mu_s  = s[b*512 + c];
    float std_s = s[b*512 + 256 + c];
    float sc = std_s * inv;
    scale[b*256 + c] = sc;
    shift[b*256 + c] = mu_s - sc * mean;
  }
}

// ---------------- weight transpose+cvt (K x N f32) -> (N x K bf16) ----------
__global__ __launch_bounds__(256) void k_tr(
    const float* __restrict__ in, bf16* __restrict__ out, int K, int N) {
  __shared__ float t[32][33];
  int bx = blockIdx.x * 32, by = blockIdx.y * 32;
  int tx = threadIdx.x & 31, ty = threadIdx.x >> 5;
  #pragma unroll
  for (int r = 0; r < 32; r += 8)
    t[ty + r][tx] = in[(size_t)(by + ty + r) * N + bx + tx];
  __syncthreads();
  #pragma unroll
  for (int r = 0; r < 32; r += 8)
    out[(size_t)(bx + ty + r) * K + by + tx] = (bf16)t[tx][ty + r];
}

// ---------------- GEMM staging ----------------------------------------------
// LDS tile 128x64 bf16, XOR-swizzled (chunk ^= row&7).
// Plain bf16 path: global_load_lds 16B, linear LDS dest + inverse-swizzled
// global source (same involution as the read side).
DEVINL void stage_lds(bf16* dst, const bf16* __restrict__ src, int ld,
                      int row0, int k0, int tid) {
  int w = tid >> 6, l = tid & 63;
  #pragma unroll
  for (int i = 0; i < 4; ++i) {
    int slot = i * 256 + w * 64 + l;
    int r = slot >> 3, cs = slot & 7;
    int c = cs ^ (r & 7);                  // inverse swizzle on SOURCE
    const bf16* g = src + (size_t)(row0 + r) * ld + k0 + c * 8;
    __builtin_amdgcn_global_load_lds(
        (const __attribute__((address_space(1))) void*)g,
        (__attribute__((address_space(3))) void*)(dst + (i * 256 + w * 64) * 8),
        16, 0, 0);
  }
}

// Transform path (f32->bf16 and/or adain): reg-stage + swizzled ds_write.
template<int AF32, int ADAIN>
DEVINL void stageA_T(bf16* sw, const void* __restrict__ srcv, int ld,
                     int row0, int k0, int tid, int bb,
                     const float* __restrict__ scale,
                     const float* __restrict__ shift) {
  #pragma unroll
  for (int i = 0; i < 4; ++i) {
    int idx = i * 256 + tid;               // 1024 8-elem chunks
    int r = idx >> 3, c = idx & 7;
    float f[8];
    if constexpr (AF32) {
      const float* p = &((const float*)srcv)[(size_t)(row0 + r) * ld + k0 + c * 8];
      f32x4 v0 = *(const f32x4*)p;
      f32x4 v1 = *(const f32x4*)(p + 4);
      f[0]=v0[0]; f[1]=v0[1]; f[2]=v0[2]; f[3]=v0[3];
      f[4]=v1[0]; f[5]=v1[1]; f[6]=v1[2]; f[7]=v1[3];
    } else {
      bf16x8v v = *(const bf16x8v*)&((const bf16*)srcv)[(size_t)(row0 + r) * ld + k0 + c * 8];
      #pragma unroll
      for (int u = 0; u < 8; ++u) f[u] = (float)v[u];
    }
    if constexpr (ADAIN) {
      const float* sc = &scale[bb * 256 + k0 + c * 8];
      const float* sh = &shift[bb * 256 + k0 + c * 8];
      #pragma unroll
      for (int u = 0; u < 8; ++u) f[u] = sh[u] + sc[u] * f[u];
    }
    bf16x8v o;
    #pragma unroll
    for (int u = 0; u < 8; ++u) o[u] = (bf16)f[u];
    *(bf16x8v*)&sw[r * 64 + ((c ^ (r & 7)) * 8)] = o;
  }
}

// ---------------- GEMM: out = [adain(A)] @ Bt^T + bias (+res, gelu) ---------
// 1D grid with XCD-bijective swizzle; gx = column-tiles.
// RESMODE: 0 none, 1 f32, 2 bf16. OUTF32: 1 f32 out, 0 bf16 out.
template<int AF32, int ADAIN, int RESMODE, int GELU, int OUTF32>
__global__ __launch_bounds__(256) void k_gemm(
    const void* __restrict__ Av, const bf16* __restrict__ Bt,
    const float* __restrict__ bias, const void* __restrict__ resv,
    const float* __restrict__ scale, const float* __restrict__ shift,
    void* __restrict__ outv, int N, int K, int row_off, int gx) {
  __shared__ bf16 a_sw[128 * 64];
  __shared__ bf16 b_sw[128 * 64];
  int tid = threadIdx.x;
  int l = tid & 63, w = tid >> 6;
  int wr = w >> 1, wc = w & 1;             // 2x2 waves, 64x64 each
  int lm = l & 15, lg = l >> 4;

  // XCD-aware bijective swizzle (grid always a multiple of 8 here)
  int nwg = gridDim.x;
  int lin = blockIdx.x;
  int swz = (lin & 7) * (nwg >> 3) + (lin >> 3);
  int bx = swz % gx, by = swz / gx;
  int m0 = by * 128, n0 = bx * 128;
  int bb = (m0 + row_off) >> 12;           // batch (tiles never straddle)

  f32x4 acc[4][4];
  #pragma unroll
  for (int mi = 0; mi < 4; ++mi)
    #pragma unroll
    for (int ni = 0; ni < 4; ++ni)
      acc[mi][ni] = (f32x4){0.f, 0.f, 0.f, 0.f};

  for (int k0 = 0; k0 < K; k0 += 64) {
    if constexpr (AF32 || ADAIN)
      stageA_T<AF32, ADAIN>(a_sw, Av, K, m0, k0, tid, bb, scale, shift);
    else
      stage_lds(a_sw, (const bf16*)Av, K, m0, k0, tid);
    stage_lds(b_sw, Bt, K, n0, k0, tid);
    __syncthreads();
    #pragma unroll
    for (int kk = 0; kk < 2; ++kk) {
      bf16x8v af[4], bv[4];
      #pragma unroll
      for (int mi = 0; mi < 4; ++mi) {
        int row = wr * 64 + mi * 16 + lm;
        af[mi] = *(const bf16x8v*)&a_sw[row * 64 + (((kk * 4 + lg) ^ (row & 7)) * 8)];
      }
      #pragma unroll
      for (int ni = 0; ni < 4; ++ni) {
        int row = wc * 64 + ni * 16 + lm;
        bv[ni] = *(const bf16x8v*)&b_sw[row * 64 + (((kk * 4 + lg) ^ (row & 7)) * 8)];
      }
      #pragma unroll
      for (int mi = 0; mi < 4; ++mi)
        #pragma unroll
        for (int ni = 0; ni < 4; ++ni)
          acc[mi][ni] = mfma16(af[mi], bv[ni], acc[mi][ni]);
    }
    __syncthreads();
  }
  #pragma unroll
  for (int mi = 0; mi < 4; ++mi) {
    #pragma unroll
    for (int ni = 0; ni < 4; ++ni) {
      int row = m0 + wr * 64 + mi * 16 + lg * 4;
      int col = n0 + wc * 64 + ni * 16 + lm;
      float bv_ = bias[col];
      #pragma unroll
      for (int j = 0; j < 4; ++j) {
        float o = acc[mi][ni][j] + bv_;
        if constexpr (RESMODE == 1)
          o += ((const float*)resv)[(size_t)(row + j) * N + col];
        if constexpr (RESMODE == 2)
          o += (float)((const bf16*)resv)[(size_t)(row + j) * N + col];
        if constexpr (GELU)
          o = 0.5f * o * (1.0f + erff(o * 0.70710678118654752f));
        if constexpr (OUTF32)
          ((float*)outv)[(size_t)(row + j) * N + col] = o;
        else
          ((bf16*)outv)[(size_t)(row + j) * N + col] = (bf16)o;
      }
    }
  }
}

// ---------------- windowed attention (both branches) ------------------------
// block = (b, window, branch); 4 waves = 4 heads (d=32), N=64 tokens.
__global__ __launch_bounds__(256) void k_attn(
    const bf16* __restrict__ qkv,
    const float* __restrict__ rpb1, const float* __restrict__ rpb2,
    bf16* __restrict__ aout) {
  __shared__ bf16 lds[27648];
  bf16* vt = lds;             // [128][72]   V transposed (d-major)
  bf16* qs = lds + 9216;      // [64][136]
  bf16* ks = lds + 17920;     // [64][136]
  bf16* ps = lds + 9216;      // [4][64][72] reuses qs/ks after frag loads

  int tid = threadIdx.x;
  int bx = blockIdx.x;
  int br = bx & 1, widx = (bx >> 1) & 63, b = bx >> 7;
  int wy = widx >> 3, wx = widx & 7;

  auto grow = [&](int tok) -> int {
    int y = wy * 8 + (tok >> 3), xc = wx * 8 + (tok & 7);
    if (br) { y = (y + 4) & 63; xc = (xc + 4) & 63; }   // shifted branch
    return b * 4096 + y * 64 + xc;
  };

  // stage Q, K row-major
  #pragma unroll
  for (int m = 0; m < 2; ++m) {
    bf16* dst = m ? ks : qs;
    int moff = m * 256 + br * 128;
    for (int it = 0; it < 4; ++it) {
      int task = it * 256 + tid;
      int tok = task >> 4, chunk = task & 15;
      bf16x8v v = *(const bf16x8v*)&qkv[(size_t)grow(tok) * 768 + moff + chunk * 8];
      *(bf16x8v*)&dst[tok * 136 + chunk * 8] = v;
    }
  }
  // stage V transposed
  for (int it = 0; it < 4; ++it) {
    int task = it * 256 + tid;
    int tok = task & 63, chunk = task >> 6;
    bf16x8v v = *(const bf16x8v*)&qkv[(size_t)grow(tok) * 768 + 512 + br * 128 + chunk * 8];
    #pragma unroll
    for (int u = 0; u < 8; ++u) vt[(chunk * 8 + u) * 72 + tok] = v[u];
  }
  __syncthreads();

  int l = tid & 63, h = tid >> 6;
  int lm = l & 15, lg = l >> 4;

  bf16x8v qa[4], kb[4];
  #pragma unroll
  for (int i = 0; i < 4; ++i) {
    qa[i] = *(const bf16x8v*)&qs[(i * 16 + lm) * 136 + h * 32 + lg * 8];
    kb[i] = *(const bf16x8v*)&ks[(i * 16 + lm) * 136 + h * 32 + lg * 8];
  }
  __syncthreads();   // all waves done with qs/ks -> ps region reusable

  f32x4 s[4][4];
  #pragma unroll
  for (int qi = 0; qi < 4; ++qi)
    #pragma unroll
    for (int ki = 0; ki < 4; ++ki)
      s[qi][ki] = mfma16(qa[qi], kb[ki], (f32x4){0.f,0.f,0.f,0.f});

  const float* rpb = br ? rpb2 : rpb1;
  bool need_mask = br && (wy == 7 || wx == 7);
  #pragma unroll
  for (int qi = 0; qi < 4; ++qi)
    #pragma unroll
    for (int ki = 0; ki < 4; ++ki)
      #pragma unroll
      for (int j = 0; j < 4; ++j) {
        int iq = qi * 16 + lg * 4 + j;     // C/D: row=(lane>>4)*4+reg
        int ik = ki * 16 + lm;             //      col=lane&15
        int dy = (iq >> 3) - (ik >> 3) + 7;
        int dx = (iq & 7) - (ik & 7) + 7;
        float val = s[qi][ki][j] * 0.17677669529663687f + rpb[(dy * 15 + dx) * 4 + h];
        if (need_mask) {
          int yq = wy * 8 + (iq >> 3), xq = wx * 8 + (iq & 7);
          int yk = wy * 8 + (ik >> 3), xk = wx * 8 + (ik & 7);
          int idq = (yq < 56 ? 0 : (yq < 60 ? 1 : 2)) * 3 + (xq < 56 ? 0 : (xq < 60 ? 1 : 2));
          int idk = (yk < 56 ? 0 : (yk < 60 ? 1 : 2)) * 3 + (xk < 56 ? 0 : (xk < 60 ? 1 : 2));
          if (idq != idk) val -= 100.0f;
        }
        s[qi][ki][j] = val;
      }

  // softmax per q-row (cols spread over 16 lanes x 4 ki frags)
  #pragma unroll
  for (int qi = 0; qi < 4; ++qi)
    #pragma unroll
    for (int j = 0; j < 4; ++j) {
      float mx = fmaxf(fmaxf(s[qi][0][j], s[qi][1][j]), fmaxf(s[qi][2][j], s[qi][3][j]));
      #pragma unroll
      for (int mk = 1; mk <= 8; mk <<= 1) mx = fmaxf(mx, __shfl_xor(mx, mk));
      float sum = 0.f;
      #pragma unroll
      for (int ki = 0; ki < 4; ++ki) {
        float e = __expf(s[qi][ki][j] - mx);
        s[qi][ki][j] = e;
        sum += e;
      }
      #pragma unroll
      for (int mk = 1; mk <= 8; mk <<= 1) sum += __shfl_xor(sum, mk);
      float rs = 1.0f / sum;
      #pragma unroll
      for (int ki = 0; ki < 4; ++ki) s[qi][ki][j] *= rs;
    }

  // P -> per-wave LDS (bf16), then PV
  bf16* pw = ps + h * 4608;
  #pragma unroll
  for (int qi = 0; qi < 4; ++qi)
    #pragma unroll
    for (int ki = 0; ki < 4; ++ki)
      #pragma unroll
      for (int j = 0; j < 4; ++j)
        pw[(qi * 16 + lg * 4 + j) * 72 + ki * 16 + lm] = (bf16)s[qi][ki][j];

  f32x4 o[4][2];
  #pragma unroll
  for (int qi = 0; qi < 4; ++qi) {
    o[qi][0] = (f32x4){0.f,0.f,0.f,0.f};
    o[qi][1] = (f32x4){0.f,0.f,0.f,0.f};
  }
  #pragma unroll
  for (int kk = 0; kk < 2; ++kk) {
    bf16x8v pa[4], vb[2];
    #pragma unroll
    for (int qi = 0; qi < 4; ++qi)
      pa[qi] = *(const bf16x8v*)&pw[(qi * 16 + lm) * 72 + kk * 32 + lg * 8];
    #pragma unroll
    for (int ni = 0; ni < 2; ++ni)
      vb[ni] = *(const bf16x8v*)&vt[(h * 32 + ni * 16 + lm) * 72 + kk * 32 + lg * 8];
    #pragma unroll
    for (int qi = 0; qi < 4; ++qi)
      #pragma unroll
      for (int ni = 0; ni < 2; ++ni)
        o[qi][ni] = mfma16(pa[qi], vb[ni], o[qi][ni]);
  }

  #pragma unroll
  for (int qi = 0; qi < 4; ++qi)
    #pragma unroll
    for (int ni = 0; ni < 2; ++ni)
      #pragma unroll
      for (int j = 0; j < 4; ++j) {
        int tok = qi * 16 + lg * 4 + j;
        int row = grow(tok);
        int col = br * 128 + h * 32 + ni * 16 + lm;
        aout[(size_t)row * 256 + col] = (bf16)o[qi][ni][j];
      }
}

// ---------------- host ------------------------------------------------------
extern "C" void kernel_launch(void* const* d_in, const int* in_sizes, int n_in,
                              void* d_out, int out_size, void* d_ws, size_t ws_size,
                              hipStream_t stream) {
  (void)in_sizes; (void)n_in; (void)out_size; (void)ws_size;
  const float* x      = (const float*)d_in[0];
  const float* style  = (const float*)d_in[1];
  const float* w_qkv  = (const float*)d_in[2];
  const float* b_qkv  = (const float*)d_in[3];
  const float* w_proj = (const float*)d_in[4];
  const float* b_proj = (const float*)d_in[5];
  const float* w_ada1 = (const float*)d_in[6];
  const float* b_ada1 = (const float*)d_in[7];
  const float* w_ada2 = (const float*)d_in[8];
  const float* b_ada2 = (const float*)d_in[9];
  const float* rpb1   = (const float*)d_in[10];
  const float* rpb2   = (const float*)d_in[11];
  const float* w_fc1  = (const float*)d_in[12];
  const float* b_fc1  = (const float*)d_in[13];
  const float* w_fc2  = (const float*)d_in[14];
  const float* b_fc2  = (const float*)d_in[15];

  char* ws = (char*)d_ws;
  float* s1     = (float*)(ws + 0);
  float* s2     = (float*)(ws + 32768);
  float* scale1 = (float*)(ws + 65536);
  float* shift1 = (float*)(ws + 81920);
  float* scale2 = (float*)(ws + 98304);
  float* shift2 = (float*)(ws + 114688);
  bf16* wtqkv   = (bf16*)(ws + 131072);            // 768x256 bf16
  bf16* wtproj  = (bf16*)(ws + 524288);            // 256x256
  bf16* wtfc1   = (bf16*)(ws + 655360);            // 1024x256
  bf16* wtfc2   = (bf16*)(ws + 1179648);           // 256x1024
  const size_t BIG = 2097152;
  bf16* qkv  = (bf16*)(ws + BIG);                  // 65536x768 bf16 (100.7MB)
  bf16* attn = (bf16*)(ws + BIG + 100663296);      // 65536x256 bf16 (33.5MB)
  bf16* x1   = (bf16*)(ws + BIG);                  // 65536x256 bf16 (reuses qkv)
  bf16* g    = (bf16*)(ws + BIG + 33554432);       // 32768x1024 bf16 chunk (67MB)

  // weight transposes (f32 -> bf16)
  k_tr<<<dim3(24, 8),  256, 0, stream>>>(w_qkv,  wtqkv,  256, 768);
  k_tr<<<dim3(8, 8),   256, 0, stream>>>(w_proj, wtproj, 256, 256);
  k_tr<<<dim3(32, 8),  256, 0, stream>>>(w_fc1,  wtfc1,  256, 1024);
  k_tr<<<dim3(8, 32),  256, 0, stream>>>(w_fc2,  wtfc2,  1024, 256);

  // style projections, adain1 params
  k_style<<<64, 256, 0, stream>>>(style, w_ada1, b_ada1, w_ada2, b_ada2, s1, s2);
  k_stats<1><<<dim3(4, 16), 256, 0, stream>>>(x, s1, scale1, shift1);

  // qkv = adain1(x) @ w_qkv + b_qkv           (A f32+adain, out bf16)
  k_gemm<1,1,0,0,0><<<3072, 256, 0, stream>>>(
      x, wtqkv, b_qkv, nullptr, scale1, shift1, qkv, 768, 256, 0, 6);

  // windowed attention (both branches)
  k_attn<<<2048, 256, 0, stream>>>(qkv, rpb1, rpb2, attn);

  // x1 = x + attn @ w_proj + b_proj           (A bf16 gload_lds, res f32)
  k_gemm<0,0,1,0,0><<<1024, 256, 0, stream>>>(
      attn, wtproj, b_proj, x, nullptr, nullptr, x1, 256, 256, 0, 2);

  // adain2 params from x1 (bf16)
  k_stats<0><<<dim3(4, 16), 256, 0, stream>>>(x1, s2, scale2, shift2);

  // MLP in 2 row-chunks of 32768 (g reuses dead qkv tail region)
  for (int ch = 0; ch < 2; ++ch) {
    size_t ro = (size_t)ch * 32768;
    // g = gelu(adain2(x1) @ w_fc1 + b_fc1)    (A bf16+adain, out bf16)
    k_gemm<0,1,0,1,0><<<2048, 256, 0, stream>>>(
        x1 + ro * 256, wtfc1, b_fc1, nullptr, scale2, shift2,
        g, 1024, 256, (int)ro, 8);
    // out = x1 + g @ w_fc2 + b_fc2            (A bf16 gload_lds, res bf16, out f32)
    k_gemm<0,0,2,0,1><<<512, 256, 0, stream>>>(
        g, wtfc2, b_fc2, x1 + ro * 256, nullptr, nullptr,
        (float*)d_out + ro * 256, 256, 1024, 0, 2);
  }
}

// Round 4
// 367.675 us; speedup vs baseline: 1.2347x; 1.0635x over previous
//
#include <hip/hip_runtime.h>
#include <hip/hip_bf16.h>

typedef __bf16 bf16;
typedef __bf16 bf16x4v __attribute__((ext_vector_type(4)));
typedef __bf16 bf16x8v __attribute__((ext_vector_type(8)));
typedef float f32x4 __attribute__((ext_vector_type(4)));
typedef short s16x4 __attribute__((ext_vector_type(4)));

#define DEVINL static __device__ __forceinline__

DEVINL f32x4 mfma16(bf16x8v a, bf16x8v b, f32x4 c) {
  return __builtin_amdgcn_mfma_f32_16x16x32_bf16(a, b, c, 0, 0, 0);
}

// 16x16x16 bf16 MFMA: A/B frag = 4 bf16 (k = (l>>4)*4+u), C/D standard.
DEVINL f32x4 mfma16x16(bf16x4v a, bf16x4v b, f32x4 c) {
#if __has_builtin(__builtin_amdgcn_mfma_f32_16x16x16bf16_1k)
  return __builtin_amdgcn_mfma_f32_16x16x16bf16_1k(
      __builtin_bit_cast(s16x4, a), __builtin_bit_cast(s16x4, b), c, 0, 0, 0);
#else
  f32x4 d;
  asm("v_mfma_f32_16x16x16_bf16 %0, %1, %2, %3"
      : "=v"(d) : "v"(a), "v"(b), "v"(c));
  return d;
#endif
}

// ---------------- style projections: s = style @ w_ada + b_ada (f32) --------
__global__ __launch_bounds__(256) void k_style(
    const float* __restrict__ style,
    const float* __restrict__ wa1, const float* __restrict__ ba1,
    const float* __restrict__ wa2, const float* __restrict__ ba2,
    float* __restrict__ s1, float* __restrict__ s2) {
  int idx = blockIdx.x * 256 + threadIdx.x;   // 2*16*512 = 16384
  int which = idx >> 13;
  int r = idx & 8191;
  int b = r >> 9, n = r & 511;
  const float* wa = which ? wa2 : wa1;
  const float* ba = which ? ba2 : ba1;
  const float* srow = style + b * 512;
  float acc = ba[n];
  for (int k = 0; k < 512; ++k)
    acc += srow[k] * wa[k * 512 + n];
  (which ? s2 : s1)[b * 512 + n] = acc;
}

// ---------------- stats pass 1: per (b, row-chunk) partial sum/sumsq --------
template<int F32>
__global__ __launch_bounds__(256) void k_stats_part(
    const void* __restrict__ xv, float* __restrict__ psum,
    float* __restrict__ psq) {
  int rc = blockIdx.x, b = blockIdx.y;        // 16 x 16
  int c = threadIdx.x;
  size_t base = (size_t)b * 4096 * 256 + (size_t)rc * 256 * 256 + c;
  float sm = 0.f, q = 0.f;
  #pragma unroll 4
  for (int r = 0; r < 256; ++r) {
    float f;
    if constexpr (F32) f = ((const float*)xv)[base + (size_t)r * 256];
    else               f = (float)((const bf16*)xv)[base + (size_t)r * 256];
    sm += f; q += f * f;
  }
  int o = (b * 16 + rc) * 256 + c;
  psum[o] = sm; psq[o] = q;
}

// ---------------- stats pass 2: combine + adain scale/shift -----------------
__global__ __launch_bounds__(256) void k_stats_fin(
    const float* __restrict__ psum, const float* __restrict__ psq,
    const float* __restrict__ s,
    float* __restrict__ scale, float* __restrict__ shift) {
  int b = blockIdx.x, c = threadIdx.x;
  float S = 0.f, Q = 0.f;
  #pragma unroll
  for (int rc = 0; rc < 16; ++rc) {
    S += psum[(b * 16 + rc) * 256 + c];
    Q += psq[(b * 16 + rc) * 256 + c];
  }
  float mean = S * (1.0f/4096.0f);
  float var  = Q * (1.0f/4096.0f) - mean * mean;
  float inv  = rsqrtf(var + 1e-5f);
  float mu_s  = s[b * 512 + c];
  float std_s = s[b * 512 + 256 + c];
  float sc = std_s * inv;
  scale[b * 256 + c] = sc;
  shift[b * 256 + c] = mu_s - sc * mean;
}

// ---------------- weight transpose+cvt (K x N f32) -> (N x K bf16) ----------
__global__ __launch_bounds__(256) void k_tr(
    const float* __restrict__ in, bf16* __restrict__ out, int K, int N) {
  __shared__ float t[32][33];
  int bx = blockIdx.x * 32, by = blockIdx.y * 32;
  int tx = threadIdx.x & 31, ty = threadIdx.x >> 5;
  #pragma unroll
  for (int r = 0; r < 32; r += 8)
    t[ty + r][tx] = in[(size_t)(by + ty + r) * N + bx + tx];
  __syncthreads();
  #pragma unroll
  for (int r = 0; r < 32; r += 8)
    out[(size_t)(bx + ty + r) * K + by + tx] = (bf16)t[tx][ty + r];
}

// ---------------- GEMM staging ----------------------------------------------
// LDS tile 128x64 bf16, XOR-swizzled (chunk ^= row&7).
DEVINL void stage_lds(bf16* dst, const bf16* __restrict__ src, int ld,
                      int row0, int k0, int tid) {
  int w = tid >> 6, l = tid & 63;
  #pragma unroll
  for (int i = 0; i < 4; ++i) {
    int slot = i * 256 + w * 64 + l;
    int r = slot >> 3, cs = slot & 7;
    int c = cs ^ (r & 7);                  // inverse swizzle on SOURCE
    const bf16* g = src + (size_t)(row0 + r) * ld + k0 + c * 8;
    __builtin_amdgcn_global_load_lds(
        (const __attribute__((address_space(1))) void*)g,
        (__attribute__((address_space(3))) void*)(dst + (i * 256 + w * 64) * 8),
        16, 0, 0);
  }
}

template<int AF32, int ADAIN>
DEVINL void stageA_T(bf16* sw, const void* __restrict__ srcv, int ld,
                     int row0, int k0, int tid, int bb,
                     const float* __restrict__ scale,
                     const float* __restrict__ shift) {
  #pragma unroll
  for (int i = 0; i < 4; ++i) {
    int idx = i * 256 + tid;               // 1024 8-elem chunks
    int r = idx >> 3, c = idx & 7;
    float f[8];
    if constexpr (AF32) {
      const float* p = &((const float*)srcv)[(size_t)(row0 + r) * ld + k0 + c * 8];
      f32x4 v0 = *(const f32x4*)p;
      f32x4 v1 = *(const f32x4*)(p + 4);
      f[0]=v0[0]; f[1]=v0[1]; f[2]=v0[2]; f[3]=v0[3];
      f[4]=v1[0]; f[5]=v1[1]; f[6]=v1[2]; f[7]=v1[3];
    } else {
      bf16x8v v = *(const bf16x8v*)&((const bf16*)srcv)[(size_t)(row0 + r) * ld + k0 + c * 8];
      #pragma unroll
      for (int u = 0; u < 8; ++u) f[u] = (float)v[u];
    }
    if constexpr (ADAIN) {
      const float* sc = &scale[bb * 256 + k0 + c * 8];
      const float* sh = &shift[bb * 256 + k0 + c * 8];
      #pragma unroll
      for (int u = 0; u < 8; ++u) f[u] = sh[u] + sc[u] * f[u];
    }
    bf16x8v o;
    #pragma unroll
    for (int u = 0; u < 8; ++u) o[u] = (bf16)f[u];
    *(bf16x8v*)&sw[r * 64 + ((c ^ (r & 7)) * 8)] = o;
  }
}

// ---------------- GEMM: out = [adain(A)] @ Bt^T + bias (+res, gelu) ---------
template<int AF32, int ADAIN, int RESMODE, int GELU, int OUTF32>
__global__ __launch_bounds__(256) void k_gemm(
    const void* __restrict__ Av, const bf16* __restrict__ Bt,
    const float* __restrict__ bias, const void* __restrict__ resv,
    const float* __restrict__ scale, const float* __restrict__ shift,
    void* __restrict__ outv, int N, int K, int row_off, int gx) {
  __shared__ bf16 a_sw[128 * 64];
  __shared__ bf16 b_sw[128 * 64];
  int tid = threadIdx.x;
  int l = tid & 63, w = tid >> 6;
  int wr = w >> 1, wc = w & 1;             // 2x2 waves, 64x64 each
  int lm = l & 15, lg = l >> 4;

  int nwg = gridDim.x;
  int lin = blockIdx.x;
  int swz = (lin & 7) * (nwg >> 3) + (lin >> 3);
  int bx = swz % gx, by = swz / gx;
  int m0 = by * 128, n0 = bx * 128;
  int bb = (m0 + row_off) >> 12;

  f32x4 acc[4][4];
  #pragma unroll
  for (int mi = 0; mi < 4; ++mi)
    #pragma unroll
    for (int ni = 0; ni < 4; ++ni)
      acc[mi][ni] = (f32x4){0.f, 0.f, 0.f, 0.f};

  for (int k0 = 0; k0 < K; k0 += 64) {
    if constexpr (AF32 || ADAIN)
      stageA_T<AF32, ADAIN>(a_sw, Av, K, m0, k0, tid, bb, scale, shift);
    else
      stage_lds(a_sw, (const bf16*)Av, K, m0, k0, tid);
    stage_lds(b_sw, Bt, K, n0, k0, tid);
    __syncthreads();
    #pragma unroll
    for (int kk = 0; kk < 2; ++kk) {
      bf16x8v af[4], bv[4];
      #pragma unroll
      for (int mi = 0; mi < 4; ++mi) {
        int row = wr * 64 + mi * 16 + lm;
        af[mi] = *(const bf16x8v*)&a_sw[row * 64 + (((kk * 4 + lg) ^ (row & 7)) * 8)];
      }
      #pragma unroll
      for (int ni = 0; ni < 4; ++ni) {
        int row = wc * 64 + ni * 16 + lm;
        bv[ni] = *(const bf16x8v*)&b_sw[row * 64 + (((kk * 4 + lg) ^ (row & 7)) * 8)];
      }
      #pragma unroll
      for (int mi = 0; mi < 4; ++mi)
        #pragma unroll
        for (int ni = 0; ni < 4; ++ni)
          acc[mi][ni] = mfma16(af[mi], bv[ni], acc[mi][ni]);
    }
    __syncthreads();
  }
  #pragma unroll
  for (int mi = 0; mi < 4; ++mi) {
    #pragma unroll
    for (int ni = 0; ni < 4; ++ni) {
      int row = m0 + wr * 64 + mi * 16 + lg * 4;
      int col = n0 + wc * 64 + ni * 16 + lm;
      float bv_ = bias[col];
      #pragma unroll
      for (int j = 0; j < 4; ++j) {
        float o = acc[mi][ni][j] + bv_;
        if constexpr (RESMODE == 1)
          o += ((const float*)resv)[(size_t)(row + j) * N + col];
        if constexpr (RESMODE == 2)
          o += (float)((const bf16*)resv)[(size_t)(row + j) * N + col];
        if constexpr (GELU)
          o = 0.5f * o * (1.0f + erff(o * 0.70710678118654752f));
        if constexpr (OUTF32)
          ((float*)outv)[(size_t)(row + j) * N + col] = o;
        else
          ((bf16*)outv)[(size_t)(row + j) * N + col] = (bf16)o;
      }
    }
  }
}

// ---------------- windowed attention (both branches) ------------------------
// block = (b, window, branch); 4 waves = 4 heads (d=32), 64 tokens.
// Swapped QK^T (S^T in regs) -> softmax with 2 shuffles -> in-register P
// feeding 16x16x16 PV MFMAs. Only V is staged in LDS (transposed).
__global__ __launch_bounds__(256) void k_attn(
    const bf16* __restrict__ qkv,
    const float* __restrict__ rpb1, const float* __restrict__ rpb2,
    bf16* __restrict__ aout) {
  __shared__ bf16 vt[128 * 72];   // V^T: [channel][token(+pad)]

  int tid = threadIdx.x;
  int bx = blockIdx.x;
  int br = bx & 1, widx = (bx >> 1) & 63, b = bx >> 7;
  int wy = widx >> 3, wx = widx & 7;

  auto grow = [&](int tok) -> int {
    int y = wy * 8 + (tok >> 3), xc = wx * 8 + (tok & 7);
    if (br) { y = (y + 4) & 63; xc = (xc + 4) & 63; }   // shifted branch
    return b * 4096 + y * 64 + xc;
  };

  // stage V transposed
  #pragma unroll
  for (int it = 0; it < 4; ++it) {
    int task = it * 256 + tid;
    int tok = task & 63, chunk = task >> 6;
    bf16x8v v = *(const bf16x8v*)&qkv[(size_t)grow(tok) * 768 + 512 + br * 128 + chunk * 8];
    #pragma unroll
    for (int u = 0; u < 8; ++u) vt[(chunk * 8 + u) * 72 + tok] = v[u];
  }

  int l = tid & 63, h = tid >> 6;
  int lm = l & 15, lg = l >> 4;

  // K frags (A-operand, rows = k-tokens) and Q frags (B-operand, cols = q)
  bf16x8v kb[4], qa[4];
  #pragma unroll
  for (int i = 0; i < 4; ++i) {
    kb[i] = *(const bf16x8v*)&qkv[(size_t)grow(i * 16 + lm) * 768 + 256 + br * 128 + h * 32 + lg * 8];
    qa[i] = *(const bf16x8v*)&qkv[(size_t)grow(i * 16 + lm) * 768 +       br * 128 + h * 32 + lg * 8];
  }
  __syncthreads();   // vt ready

  // V B-frags for 16x16x16 PV: col=d=lm, k-token = ki*16 + lg*4 + u
  bf16x4v vb[2][4];
  #pragma unroll
  for (int ni = 0; ni < 2; ++ni)
    #pragma unroll
    for (int ki = 0; ki < 4; ++ki)
      vb[ni][ki] = *(const bf16x4v*)&vt[(h * 32 + ni * 16 + lm) * 72 + ki * 16 + lg * 4];

  const float* rpb = br ? rpb2 : rpb1;
  bool need_mask = br && (wy == 7 || wx == 7);

  #pragma unroll
  for (int qi = 0; qi < 4; ++qi) {
    // S^T block: row = k-token, col = q-token
    f32x4 s[4];
    #pragma unroll
    for (int ki = 0; ki < 4; ++ki)
      s[ki] = mfma16(kb[ki], qa[qi], (f32x4){0.f,0.f,0.f,0.f});

    int iq = qi * 16 + lm;               // q-token (col = lane&15)
    #pragma unroll
    for (int ki = 0; ki < 4; ++ki)
      #pragma unroll
      for (int j = 0; j < 4; ++j) {
        int ik = ki * 16 + lg * 4 + j;   // k-token (row)
        int dy = (iq >> 3) - (ik >> 3) + 7;
        int dx = (iq & 7) - (ik & 7) + 7;
        float val = s[ki][j] * 0.17677669529663687f + rpb[(dy * 15 + dx) * 4 + h];
        if (need_mask) {
          int yq = wy * 8 + (iq >> 3), xq = wx * 8 + (iq & 7);
          int yk = wy * 8 + (ik >> 3), xk = wx * 8 + (ik & 7);
          int idq = (yq < 56 ? 0 : (yq < 60 ? 1 : 2)) * 3 + (xq < 56 ? 0 : (xq < 60 ? 1 : 2));
          int idk = (yk < 56 ? 0 : (yk < 60 ? 1 : 2)) * 3 + (xk < 56 ? 0 : (xk < 60 ? 1 : 2));
          if (idq != idk) val -= 100.0f;
        }
        s[ki][j] = val;
      }

    // softmax over k for fixed q: 15 in-lane max + 2 shfl, same for sum
    float mx = s[0][0];
    #pragma unroll
    for (int ki = 0; ki < 4; ++ki)
      #pragma unroll
      for (int j = 0; j < 4; ++j) mx = fmaxf(mx, s[ki][j]);
    mx = fmaxf(mx, __shfl_xor(mx, 16));
    mx = fmaxf(mx, __shfl_xor(mx, 32));
    float sum = 0.f;
    #pragma unroll
    for (int ki = 0; ki < 4; ++ki)
      #pragma unroll
      for (int j = 0; j < 4; ++j) {
        float e = __expf(s[ki][j] - mx);
        s[ki][j] = e;
        sum += e;
      }
    sum += __shfl_xor(sum, 16);
    sum += __shfl_xor(sum, 32);
    float rs = 1.0f / sum;

    // P in registers as 16x16x16 A-frags (row=q=lm, k=(l>>4)*4+u)
    bf16x4v pa[4];
    #pragma unroll
    for (int ki = 0; ki < 4; ++ki)
      #pragma unroll
      for (int j = 0; j < 4; ++j)
        pa[ki][j] = (bf16)(s[ki][j] * rs);

    // PV: out[q][d], accumulate over ki
    f32x4 o[2] = {(f32x4){0.f,0.f,0.f,0.f}, (f32x4){0.f,0.f,0.f,0.f}};
    #pragma unroll
    for (int ki = 0; ki < 4; ++ki) {
      o[0] = mfma16x16(pa[ki], vb[0][ki], o[0]);
      o[1] = mfma16x16(pa[ki], vb[1][ki], o[1]);
    }

    // write: D layout row = lg*4+j (q within block), col = lm (d within 16)
    #pragma unroll
    for (int ni = 0; ni < 2; ++ni)
      #pragma unroll
      for (int j = 0; j < 4; ++j) {
        int tok = qi * 16 + lg * 4 + j;
        int col = br * 128 + h * 32 + ni * 16 + lm;
        aout[(size_t)grow(tok) * 256 + col] = (bf16)o[ni][j];
      }
  }
}

// ---------------- host ------------------------------------------------------
extern "C" void kernel_launch(void* const* d_in, const int* in_sizes, int n_in,
                              void* d_out, int out_size, void* d_ws, size_t ws_size,
                              hipStream_t stream) {
  (void)in_sizes; (void)n_in; (void)out_size; (void)ws_size;
  const float* x      = (const float*)d_in[0];
  const float* style  = (const float*)d_in[1];
  const float* w_qkv  = (const float*)d_in[2];
  const float* b_qkv  = (const float*)d_in[3];
  const float* w_proj = (const float*)d_in[4];
  const float* b_proj = (const float*)d_in[5];
  const float* w_ada1 = (const float*)d_in[6];
  const float* b_ada1 = (const float*)d_in[7];
  const float* w_ada2 = (const float*)d_in[8];
  const float* b_ada2 = (const float*)d_in[9];
  const float* rpb1   = (const float*)d_in[10];
  const float* rpb2   = (const float*)d_in[11];
  const float* w_fc1  = (const float*)d_in[12];
  const float* b_fc1  = (const float*)d_in[13];
  const float* w_fc2  = (const float*)d_in[14];
  const float* b_fc2  = (const float*)d_in[15];

  char* ws = (char*)d_ws;
  float* s1     = (float*)(ws + 0);
  float* s2     = (float*)(ws + 32768);
  float* scale1 = (float*)(ws + 65536);
  float* shift1 = (float*)(ws + 81920);
  float* scale2 = (float*)(ws + 98304);
  float* shift2 = (float*)(ws + 114688);
  bf16* wtqkv   = (bf16*)(ws + 131072);            // 768x256 bf16
  bf16* wtproj  = (bf16*)(ws + 524288);            // 256x256
  bf16* wtfc1   = (bf16*)(ws + 655360);            // 1024x256
  bf16* wtfc2   = (bf16*)(ws + 1179648);           // 256x1024
  float* psum   = (float*)(ws + 1703936);          // 16*16*256 f32
  float* psq    = (float*)(ws + 1966080);
  const size_t BIG = 2228224;
  bf16* qkv  = (bf16*)(ws + BIG);                  // 65536x768 bf16 (100.7MB)
  bf16* attn = (bf16*)(ws + BIG + 100663296);      // 65536x256 bf16 (33.5MB)
  bf16* x1   = (bf16*)(ws + BIG);                  // 65536x256 (reuses dead qkv)
  bf16* g    = (bf16*)(ws + BIG + 33554432);       // 32768x1024 chunk (67MB)

  // weight transposes (f32 -> bf16)
  k_tr<<<dim3(24, 8),  256, 0, stream>>>(w_qkv,  wtqkv,  256, 768);
  k_tr<<<dim3(8, 8),   256, 0, stream>>>(w_proj, wtproj, 256, 256);
  k_tr<<<dim3(32, 8),  256, 0, stream>>>(w_fc1,  wtfc1,  256, 1024);
  k_tr<<<dim3(8, 32),  256, 0, stream>>>(w_fc2,  wtfc2,  1024, 256);

  // style projections, adain1 params
  k_style<<<64, 256, 0, stream>>>(style, w_ada1, b_ada1, w_ada2, b_ada2, s1, s2);
  k_stats_part<1><<<dim3(16, 16), 256, 0, stream>>>(x, psum, psq);
  k_stats_fin<<<16, 256, 0, stream>>>(psum, psq, s1, scale1, shift1);

  // qkv = adain1(x) @ w_qkv + b_qkv           (A f32+adain, out bf16)
  k_gemm<1,1,0,0,0><<<3072, 256, 0, stream>>>(
      x, wtqkv, b_qkv, nullptr, scale1, shift1, qkv, 768, 256, 0, 6);

  // windowed attention (both branches)
  k_attn<<<2048, 256, 0, stream>>>(qkv, rpb1, rpb2, attn);

  // x1 = x + attn @ w_proj + b_proj           (A bf16 gload_lds, res f32)
  k_gemm<0,0,1,0,0><<<1024, 256, 0, stream>>>(
      attn, wtproj, b_proj, x, nullptr, nullptr, x1, 256, 256, 0, 2);

  // adain2 params from x1 (bf16)
  k_stats_part<0><<<dim3(16, 16), 256, 0, stream>>>(x1, psum, psq);
  k_stats_fin<<<16, 256, 0, stream>>>(psum, psq, s2, scale2, shift2);

  // MLP in 2 row-chunks of 32768 (g reuses dead qkv tail region)
  for (int ch = 0; ch < 2; ++ch) {
    size_t ro = (size_t)ch * 32768;
    // g = gelu(adain2(x1) @ w_fc1 + b_fc1)    (A bf16+adain, out bf16)
    k_gemm<0,1,0,1,0><<<2048, 256, 0, stream>>>(
        x1 + ro * 256, wtfc1, b_fc1, nullptr, scale2, shift2,
        g, 1024, 256, (int)ro, 8);
    // out = x1 + g @ w_fc2 + b_fc2            (A bf16 gload_lds, res bf16, out f32)
    k_gemm<0,0,2,0,1><<<512, 256, 0, stream>>>(
        g, wtfc2, b_fc2, x1 + ro * 256, nullptr, nullptr,
        (float*)d_out + ro * 256, 256, 1024, 0, 2);
  }
}

// Round 5
// 360.460 us; speedup vs baseline: 1.2594x; 1.0200x over previous
//
#include <hip/hip_runtime.h>
#include <hip/hip_bf16.h>

typedef __bf16 bf16;
typedef __bf16 bf16x4v __attribute__((ext_vector_type(4)));
typedef __bf16 bf16x8v __attribute__((ext_vector_type(8)));
typedef float f32x4 __attribute__((ext_vector_type(4)));
typedef short s16x4 __attribute__((ext_vector_type(4)));

#define DEVINL static __device__ __forceinline__

DEVINL f32x4 mfma16(bf16x8v a, bf16x8v b, f32x4 c) {
  return __builtin_amdgcn_mfma_f32_16x16x32_bf16(a, b, c, 0, 0, 0);
}

// 16x16x16 bf16 MFMA: A/B frag = 4 bf16 (k = (l>>4)*4+u), C/D standard.
DEVINL f32x4 mfma16x16(bf16x4v a, bf16x4v b, f32x4 c) {
#if __has_builtin(__builtin_amdgcn_mfma_f32_16x16x16bf16_1k)
  return __builtin_amdgcn_mfma_f32_16x16x16bf16_1k(
      __builtin_bit_cast(s16x4, a), __builtin_bit_cast(s16x4, b), c, 0, 0, 0);
#else
  f32x4 d;
  asm("v_mfma_f32_16x16x16_bf16 %0, %1, %2, %3"
      : "=v"(d) : "v"(a), "v"(b), "v"(c));
  return d;
#endif
}

// ---------------- style projections: s = style @ w_ada + b_ada (f32) --------
__global__ __launch_bounds__(256) void k_style(
    const float* __restrict__ style,
    const float* __restrict__ wa1, const float* __restrict__ ba1,
    const float* __restrict__ wa2, const float* __restrict__ ba2,
    float* __restrict__ s1, float* __restrict__ s2) {
  int idx = blockIdx.x * 256 + threadIdx.x;   // 2*16*512 = 16384
  int which = idx >> 13;
  int r = idx & 8191;
  int b = r >> 9, n = r & 511;
  const float* wa = which ? wa2 : wa1;
  const float* ba = which ? ba2 : ba1;
  const float* srow = style + b * 512;
  float acc = ba[n];
  for (int k = 0; k < 512; ++k)
    acc += srow[k] * wa[k * 512 + n];
  (which ? s2 : s1)[b * 512 + n] = acc;
}

// ---------------- stats pass 1: per (b, row-chunk) partial sum/sumsq --------
template<int F32>
__global__ __launch_bounds__(256) void k_stats_part(
    const void* __restrict__ xv, float* __restrict__ psum,
    float* __restrict__ psq) {
  int rc = blockIdx.x, b = blockIdx.y;        // 16 x 16
  int c = threadIdx.x;
  size_t base = (size_t)b * 4096 * 256 + (size_t)rc * 256 * 256 + c;
  float sm = 0.f, q = 0.f;
  #pragma unroll 4
  for (int r = 0; r < 256; ++r) {
    float f;
    if constexpr (F32) f = ((const float*)xv)[base + (size_t)r * 256];
    else               f = (float)((const bf16*)xv)[base + (size_t)r * 256];
    sm += f; q += f * f;
  }
  int o = (b * 16 + rc) * 256 + c;
  psum[o] = sm; psq[o] = q;
}

// ---------------- stats pass 2: combine + adain scale/shift -----------------
__global__ __launch_bounds__(256) void k_stats_fin(
    const float* __restrict__ psum, const float* __restrict__ psq,
    const float* __restrict__ s,
    float* __restrict__ scale, float* __restrict__ shift) {
  int b = blockIdx.x, c = threadIdx.x;
  float S = 0.f, Q = 0.f;
  #pragma unroll
  for (int rc = 0; rc < 16; ++rc) {
    S += psum[(b * 16 + rc) * 256 + c];
    Q += psq[(b * 16 + rc) * 256 + c];
  }
  float mean = S * (1.0f/4096.0f);
  float var  = Q * (1.0f/4096.0f) - mean * mean;
  float inv  = rsqrtf(var + 1e-5f);
  float mu_s  = s[b * 512 + c];
  float std_s = s[b * 512 + 256 + c];
  float sc = std_s * inv;
  scale[b * 256 + c] = sc;
  shift[b * 256 + c] = mu_s - sc * mean;
}

// ---------------- adain apply: out_bf16 = shift + scale * in ----------------
template<int F32>
__global__ __launch_bounds__(256) void k_adain(
    const void* __restrict__ in, const float* __restrict__ scale,
    const float* __restrict__ shift, bf16* __restrict__ out) {
  int idx = blockIdx.x * 256 + threadIdx.x;   // 65536*32 = 2,097,152 tasks
  int c8 = idx & 31, row = idx >> 5;
  int b = row >> 12, c = c8 * 8;
  const float* scp = &scale[b * 256 + c];
  const float* shp = &shift[b * 256 + c];
  f32x4 sc0 = *(const f32x4*)scp, sc1 = *(const f32x4*)(scp + 4);
  f32x4 sh0 = *(const f32x4*)shp, sh1 = *(const f32x4*)(shp + 4);
  size_t ofs = (size_t)row * 256 + c;
  float f[8];
  if constexpr (F32) {
    f32x4 v0 = *(const f32x4*)&((const float*)in)[ofs];
    f32x4 v1 = *(const f32x4*)&((const float*)in)[ofs + 4];
    f[0]=v0[0]; f[1]=v0[1]; f[2]=v0[2]; f[3]=v0[3];
    f[4]=v1[0]; f[5]=v1[1]; f[6]=v1[2]; f[7]=v1[3];
  } else {
    bf16x8v v = *(const bf16x8v*)&((const bf16*)in)[ofs];
    #pragma unroll
    for (int u = 0; u < 8; ++u) f[u] = (float)v[u];
  }
  bf16x8v o;
  o[0]=(bf16)(sh0[0]+sc0[0]*f[0]); o[1]=(bf16)(sh0[1]+sc0[1]*f[1]);
  o[2]=(bf16)(sh0[2]+sc0[2]*f[2]); o[3]=(bf16)(sh0[3]+sc0[3]*f[3]);
  o[4]=(bf16)(sh1[0]+sc1[0]*f[4]); o[5]=(bf16)(sh1[1]+sc1[1]*f[5]);
  o[6]=(bf16)(sh1[2]+sc1[2]*f[6]); o[7]=(bf16)(sh1[3]+sc1[3]*f[7]);
  *(bf16x8v*)&out[ofs] = o;
}

// ---------------- weight transpose+cvt (K x N f32) -> (N x K bf16) ----------
__global__ __launch_bounds__(256) void k_tr(
    const float* __restrict__ in, bf16* __restrict__ out, int K, int N) {
  __shared__ float t[32][33];
  int bx = blockIdx.x * 32, by = blockIdx.y * 32;
  int tx = threadIdx.x & 31, ty = threadIdx.x >> 5;
  #pragma unroll
  for (int r = 0; r < 32; r += 8)
    t[ty + r][tx] = in[(size_t)(by + ty + r) * N + bx + tx];
  __syncthreads();
  #pragma unroll
  for (int r = 0; r < 32; r += 8)
    out[(size_t)(bx + ty + r) * K + by + tx] = (bf16)t[tx][ty + r];
}

// ---------------- GEMM staging ----------------------------------------------
// LDS tile 128x64 bf16, XOR-swizzled (chunk ^= row&7): global_load_lds 16B,
// linear LDS dest + inverse-swizzled global source (same involution as read).
DEVINL void stage_lds(bf16* dst, const bf16* __restrict__ src, int ld,
                      int row0, int k0, int tid) {
  int w = tid >> 6, l = tid & 63;
  #pragma unroll
  for (int i = 0; i < 4; ++i) {
    int slot = i * 256 + w * 64 + l;
    int r = slot >> 3, cs = slot & 7;
    int c = cs ^ (r & 7);                  // inverse swizzle on SOURCE
    const bf16* g = src + (size_t)(row0 + r) * ld + k0 + c * 8;
    __builtin_amdgcn_global_load_lds(
        (const __attribute__((address_space(1))) void*)g,
        (__attribute__((address_space(3))) void*)(dst + (i * 256 + w * 64) * 8),
        16, 0, 0);
  }
}

// ---------------- GEMM: out = A @ Bt^T + bias (+res, gelu) ------------------
// A: MxK bf16, Bt: NxK bf16. RESMODE: 0 none, 1 f32, 2 bf16. OUTF32: f32 out.
template<int RESMODE, int GELU, int OUTF32>
__global__ __launch_bounds__(256) void k_gemm(
    const bf16* __restrict__ A, const bf16* __restrict__ Bt,
    const float* __restrict__ bias, const void* __restrict__ resv,
    void* __restrict__ outv, int N, int K, int gx) {
  __shared__ bf16 a_sw[128 * 64];
  __shared__ bf16 b_sw[128 * 64];
  int tid = threadIdx.x;
  int l = tid & 63, w = tid >> 6;
  int wr = w >> 1, wc = w & 1;             // 2x2 waves, 64x64 each
  int lm = l & 15, lg = l >> 4;

  int nwg = gridDim.x;
  int lin = blockIdx.x;
  int swz = (lin & 7) * (nwg >> 3) + (lin >> 3);
  int bx = swz % gx, by = swz / gx;
  int m0 = by * 128, n0 = bx * 128;

  f32x4 acc[4][4];
  #pragma unroll
  for (int mi = 0; mi < 4; ++mi)
    #pragma unroll
    for (int ni = 0; ni < 4; ++ni)
      acc[mi][ni] = (f32x4){0.f, 0.f, 0.f, 0.f};

  for (int k0 = 0; k0 < K; k0 += 64) {
    stage_lds(a_sw, A, K, m0, k0, tid);
    stage_lds(b_sw, Bt, K, n0, k0, tid);
    __syncthreads();
    #pragma unroll
    for (int kk = 0; kk < 2; ++kk) {
      bf16x8v af[4], bv[4];
      #pragma unroll
      for (int mi = 0; mi < 4; ++mi) {
        int row = wr * 64 + mi * 16 + lm;
        af[mi] = *(const bf16x8v*)&a_sw[row * 64 + (((kk * 4 + lg) ^ (row & 7)) * 8)];
      }
      #pragma unroll
      for (int ni = 0; ni < 4; ++ni) {
        int row = wc * 64 + ni * 16 + lm;
        bv[ni] = *(const bf16x8v*)&b_sw[row * 64 + (((kk * 4 + lg) ^ (row & 7)) * 8)];
      }
      #pragma unroll
      for (int mi = 0; mi < 4; ++mi)
        #pragma unroll
        for (int ni = 0; ni < 4; ++ni)
          acc[mi][ni] = mfma16(af[mi], bv[ni], acc[mi][ni]);
    }
    __syncthreads();
  }
  #pragma unroll
  for (int mi = 0; mi < 4; ++mi) {
    #pragma unroll
    for (int ni = 0; ni < 4; ++ni) {
      int row = m0 + wr * 64 + mi * 16 + lg * 4;
      int col = n0 + wc * 64 + ni * 16 + lm;
      float bv_ = bias[col];
      #pragma unroll
      for (int j = 0; j < 4; ++j) {
        float o = acc[mi][ni][j] + bv_;
        if constexpr (RESMODE == 1)
          o += ((const float*)resv)[(size_t)(row + j) * N + col];
        if constexpr (RESMODE == 2)
          o += (float)((const bf16*)resv)[(size_t)(row + j) * N + col];
        if constexpr (GELU)
          o = 0.5f * o * (1.0f + erff(o * 0.70710678118654752f));
        if constexpr (OUTF32)
          ((float*)outv)[(size_t)(row + j) * N + col] = o;
        else
          ((bf16*)outv)[(size_t)(row + j) * N + col] = (bf16)o;
      }
    }
  }
}

// ---------------- windowed attention (both branches) ------------------------
// block = (b, window, branch); 4 waves = 4 heads (d=32), 64 tokens.
// Swapped QK^T (S^T in regs) -> 2-shuffle softmax -> in-register P feeding
// 16x16x16 PV MFMAs. Only V is staged in LDS (transposed).
__global__ __launch_bounds__(256) void k_attn(
    const bf16* __restrict__ qkv,
    const float* __restrict__ rpb1, const float* __restrict__ rpb2,
    bf16* __restrict__ aout) {
  __shared__ bf16 vt[128 * 72];   // V^T: [channel][token(+pad)]

  int tid = threadIdx.x;
  int bx = blockIdx.x;
  int br = bx & 1, widx = (bx >> 1) & 63, b = bx >> 7;
  int wy = widx >> 3, wx = widx & 7;

  auto grow = [&](int tok) -> int {
    int y = wy * 8 + (tok >> 3), xc = wx * 8 + (tok & 7);
    if (br) { y = (y + 4) & 63; xc = (xc + 4) & 63; }   // shifted branch
    return b * 4096 + y * 64 + xc;
  };

  // stage V transposed
  #pragma unroll
  for (int it = 0; it < 4; ++it) {
    int task = it * 256 + tid;
    int tok = task & 63, chunk = task >> 6;
    bf16x8v v = *(const bf16x8v*)&qkv[(size_t)grow(tok) * 768 + 512 + br * 128 + chunk * 8];
    #pragma unroll
    for (int u = 0; u < 8; ++u) vt[(chunk * 8 + u) * 72 + tok] = v[u];
  }

  int l = tid & 63, h = tid >> 6;
  int lm = l & 15, lg = l >> 4;

  // K frags (A-operand, rows = k-tokens) and Q frags (B-operand, cols = q)
  bf16x8v kb[4], qa[4];
  #pragma unroll
  for (int i = 0; i < 4; ++i) {
    kb[i] = *(const bf16x8v*)&qkv[(size_t)grow(i * 16 + lm) * 768 + 256 + br * 128 + h * 32 + lg * 8];
    qa[i] = *(const bf16x8v*)&qkv[(size_t)grow(i * 16 + lm) * 768 +       br * 128 + h * 32 + lg * 8];
  }
  __syncthreads();   // vt ready

  // V B-frags for 16x16x16 PV: col=d=lm, k-token = ki*16 + lg*4 + u
  bf16x4v vb[2][4];
  #pragma unroll
  for (int ni = 0; ni < 2; ++ni)
    #pragma unroll
    for (int ki = 0; ki < 4; ++ki)
      vb[ni][ki] = *(const bf16x4v*)&vt[(h * 32 + ni * 16 + lm) * 72 + ki * 16 + lg * 4];

  const float* rpb = br ? rpb2 : rpb1;
  bool need_mask = br && (wy == 7 || wx == 7);

  #pragma unroll
  for (int qi = 0; qi < 4; ++qi) {
    // S^T block: row = k-token, col = q-token
    f32x4 s[4];
    #pragma unroll
    for (int ki = 0; ki < 4; ++ki)
      s[ki] = mfma16(kb[ki], qa[qi], (f32x4){0.f,0.f,0.f,0.f});

    int iq = qi * 16 + lm;               // q-token (col = lane&15)
    #pragma unroll
    for (int ki = 0; ki < 4; ++ki)
      #pragma unroll
      for (int j = 0; j < 4; ++j) {
        int ik = ki * 16 + lg * 4 + j;   // k-token (row)
        int dy = (iq >> 3) - (ik >> 3) + 7;
        int dx = (iq & 7) - (ik & 7) + 7;
        float val = s[ki][j] * 0.17677669529663687f + rpb[(dy * 15 + dx) * 4 + h];
        if (need_mask) {
          int yq = wy * 8 + (iq >> 3), xq = wx * 8 + (iq & 7);
          int yk = wy * 8 + (ik >> 3), xk = wx * 8 + (ik & 7);
          int idq = (yq < 56 ? 0 : (yq < 60 ? 1 : 2)) * 3 + (xq < 56 ? 0 : (xq < 60 ? 1 : 2));
          int idk = (yk < 56 ? 0 : (yk < 60 ? 1 : 2)) * 3 + (xk < 56 ? 0 : (xk < 60 ? 1 : 2));
          if (idq != idk) val -= 100.0f;
        }
        s[ki][j] = val;
      }

    // softmax over k for fixed q: 15 in-lane max + 2 shfl, same for sum
    float mx = s[0][0];
    #pragma unroll
    for (int ki = 0; ki < 4; ++ki)
      #pragma unroll
      for (int j = 0; j < 4; ++j) mx = fmaxf(mx, s[ki][j]);
    mx = fmaxf(mx, __shfl_xor(mx, 16));
    mx = fmaxf(mx, __shfl_xor(mx, 32));
    float sum = 0.f;
    #pragma unroll
    for (int ki = 0; ki < 4; ++ki)
      #pragma unroll
      for (int j = 0; j < 4; ++j) {
        float e = __expf(s[ki][j] - mx);
        s[ki][j] = e;
        sum += e;
      }
    sum += __shfl_xor(sum, 16);
    sum += __shfl_xor(sum, 32);
    float rs = 1.0f / sum;

    // P in registers as 16x16x16 A-frags (row=q=lm, k=(l>>4)*4+u)
    bf16x4v pa[4];
    #pragma unroll
    for (int ki = 0; ki < 4; ++ki)
      #pragma unroll
      for (int j = 0; j < 4; ++j)
        pa[ki][j] = (bf16)(s[ki][j] * rs);

    // PV: out[q][d], accumulate over ki
    f32x4 o[2] = {(f32x4){0.f,0.f,0.f,0.f}, (f32x4){0.f,0.f,0.f,0.f}};
    #pragma unroll
    for (int ki = 0; ki < 4; ++ki) {
      o[0] = mfma16x16(pa[ki], vb[0][ki], o[0]);
      o[1] = mfma16x16(pa[ki], vb[1][ki], o[1]);
    }

    // write: D layout row = lg*4+j (q within block), col = lm (d within 16)
    #pragma unroll
    for (int ni = 0; ni < 2; ++ni)
      #pragma unroll
      for (int j = 0; j < 4; ++j) {
        int tok = qi * 16 + lg * 4 + j;
        int col = br * 128 + h * 32 + ni * 16 + lm;
        aout[(size_t)grow(tok) * 256 + col] = (bf16)o[ni][j];
      }
  }
}

// ---------------- host ------------------------------------------------------
extern "C" void kernel_launch(void* const* d_in, const int* in_sizes, int n_in,
                              void* d_out, int out_size, void* d_ws, size_t ws_size,
                              hipStream_t stream) {
  (void)in_sizes; (void)n_in; (void)out_size; (void)ws_size;
  const float* x      = (const float*)d_in[0];
  const float* style  = (const float*)d_in[1];
  const float* w_qkv  = (const float*)d_in[2];
  const float* b_qkv  = (const float*)d_in[3];
  const float* w_proj = (const float*)d_in[4];
  const float* b_proj = (const float*)d_in[5];
  const float* w_ada1 = (const float*)d_in[6];
  const float* b_ada1 = (const float*)d_in[7];
  const float* w_ada2 = (const float*)d_in[8];
  const float* b_ada2 = (const float*)d_in[9];
  const float* rpb1   = (const float*)d_in[10];
  const float* rpb2   = (const float*)d_in[11];
  const float* w_fc1  = (const float*)d_in[12];
  const float* b_fc1  = (const float*)d_in[13];
  const float* w_fc2  = (const float*)d_in[14];
  const float* b_fc2  = (const float*)d_in[15];

  char* ws = (char*)d_ws;
  float* s1     = (float*)(ws + 0);
  float* s2     = (float*)(ws + 32768);
  float* scale1 = (float*)(ws + 65536);
  float* shift1 = (float*)(ws + 81920);
  float* scale2 = (float*)(ws + 98304);
  float* shift2 = (float*)(ws + 114688);
  bf16* wtqkv   = (bf16*)(ws + 131072);            // 768x256 bf16
  bf16* wtproj  = (bf16*)(ws + 524288);            // 256x256
  bf16* wtfc1   = (bf16*)(ws + 655360);            // 1024x256
  bf16* wtfc2   = (bf16*)(ws + 1179648);           // 256x1024
  float* psum   = (float*)(ws + 1703936);          // 16*16*256 f32
  float* psq    = (float*)(ws + 1966080);
  const size_t BIG = 2228224;
  bf16* xn   = (bf16*)(ws + BIG);                  // 65536x256 bf16 (33.5MB)
  bf16* qkv  = (bf16*)(ws + BIG + 33554432);       // 65536x768 bf16 (100.7MB)
  bf16* attn = (bf16*)(ws + BIG + 134217728);      // 65536x256 bf16 (33.5MB)
  bf16* x1   = (bf16*)(ws + BIG + 33554432);       // overlays qkv head
  bf16* xn2  = xn;                                 // reuses xn slot
  bf16* g    = (bf16*)(ws + BIG + 67108864);       // 32768x1024 chunk, qkv tail

  // weight transposes (f32 -> bf16)
  k_tr<<<dim3(24, 8),  256, 0, stream>>>(w_qkv,  wtqkv,  256, 768);
  k_tr<<<dim3(8, 8),   256, 0, stream>>>(w_proj, wtproj, 256, 256);
  k_tr<<<dim3(32, 8),  256, 0, stream>>>(w_fc1,  wtfc1,  256, 1024);
  k_tr<<<dim3(8, 32),  256, 0, stream>>>(w_fc2,  wtfc2,  1024, 256);

  // style projections, adain1 params, adain1 apply
  k_style<<<64, 256, 0, stream>>>(style, w_ada1, b_ada1, w_ada2, b_ada2, s1, s2);
  k_stats_part<1><<<dim3(16, 16), 256, 0, stream>>>(x, psum, psq);
  k_stats_fin<<<16, 256, 0, stream>>>(psum, psq, s1, scale1, shift1);
  k_adain<1><<<8192, 256, 0, stream>>>(x, scale1, shift1, xn);

  // qkv = xn @ w_qkv + b_qkv                 (pure DMA staging)
  k_gemm<0,0,0><<<3072, 256, 0, stream>>>(
      xn, wtqkv, b_qkv, nullptr, qkv, 768, 256, 6);

  // windowed attention (both branches)
  k_attn<<<2048, 256, 0, stream>>>(qkv, rpb1, rpb2, attn);

  // x1 = x + attn @ w_proj + b_proj           (res f32, out bf16)
  k_gemm<1,0,0><<<1024, 256, 0, stream>>>(
      attn, wtproj, b_proj, x, x1, 256, 256, 2);

  // adain2 params + apply
  k_stats_part<0><<<dim3(16, 16), 256, 0, stream>>>(x1, psum, psq);
  k_stats_fin<<<16, 256, 0, stream>>>(psum, psq, s2, scale2, shift2);
  k_adain<0><<<8192, 256, 0, stream>>>(x1, scale2, shift2, xn2);

  // MLP in 2 row-chunks of 32768 (g reuses dead qkv tail region)
  for (int ch = 0; ch < 2; ++ch) {
    size_t ro = (size_t)ch * 32768;
    // g = gelu(xn2 @ w_fc1 + b_fc1)
    k_gemm<0,1,0><<<2048, 256, 0, stream>>>(
        xn2 + ro * 256, wtfc1, b_fc1, nullptr, g, 1024, 256, 8);
    // out = x1 + g @ w_fc2 + b_fc2            (res bf16, out f32)
    k_gemm<2,0,1><<<512, 256, 0, stream>>>(
        g, wtfc2, b_fc2, x1 + ro * 256,
        (float*)d_out + ro * 256, 256, 1024, 2);
  }
}